// Round 2
// baseline (939.627 us; speedup 1.0000x reference)
//
#include <hip/hip_runtime.h>
#include <math.h>

#define Nn 768
#define NN 589824          // 768*768
#define DOUT 2112

// ws float offsets
#define WS_Q   0           // [12][768][16]
#define WS_K   147456      // [12][768][16]
#define WS_V   294912      // [12][768][16]
#define WS_QP  442368      // [12][768][12]
#define WS_KP  552960      // [12][768][12]
#define WS_VP  663552      // [12][768][24]
#define WS_CAT 884736      // [768][2112]
#define WS_A   2506752     // bf16 [12][768][768] stored as u16

typedef unsigned short u16;
typedef unsigned int u32;

__device__ __forceinline__ float bf2f(u16 u) {
  union { float f; u32 i; } x; x.i = ((u32)u) << 16; return x.f;
}
__device__ __forceinline__ u16 f2bf(float f) {
  union { float f; u32 i; } x; x.f = f;
  u32 r = x.i + 0x7FFFu + ((x.i >> 16) & 1u);
  return (u16)(r >> 16);
}

// ---------------- K1: projections q,k,v + rotated points ----------------
// grid (48 i-tiles, 6 feature-groups of 192), block 256
__global__ __launch_bounds__(256) void k_proj(
    const float* __restrict__ s, const float* __restrict__ rot, const float* __restrict__ trans,
    const float* __restrict__ w_q, const float* __restrict__ b_q,
    const float* __restrict__ w_kv, const float* __restrict__ b_kv,
    const float* __restrict__ w_qp, const float* __restrict__ b_qp,
    const float* __restrict__ w_kvp, const float* __restrict__ b_kvp,
    float* __restrict__ ws)
{
  __shared__ float s16[16][384];
  __shared__ float praw[16][192];
  __shared__ float rot16[16][9];
  __shared__ float t16[16][3];
  const int t = threadIdx.x;
  const int ib = blockIdx.x, fg = blockIdx.y;
  const int i0 = ib * 16;

  {
    const float4* sp = (const float4*)(s + (size_t)i0 * 384);
    float4* dp = (float4*)&s16[0][0];
    for (int idx = t; idx < 1536; idx += 256) dp[idx] = sp[idx];
  }
  if (fg >= 3) {
    if (t < 144) rot16[t / 9][t % 9] = rot[i0 * 9 + t];
    else if (t < 192) { int g = t - 144; t16[g / 3][g % 3] = trans[i0 * 3 + g]; }
  }
  __syncthreads();

  const int rg = t >> 6;          // row group 0..3 (rows rg*4 .. rg*4+3)
  const int fl = t & 63;
  for (int p = 0; p < 3; p++) {
    const int f_loc = p * 64 + fl;        // 0..191
    const int F = fg * 192 + f_loc;       // global feature 0..1151
    const float* wrow; float bias;
    if (F < 192)      { wrow = w_q   + (size_t)F * 384;          bias = b_q[F]; }
    else if (F < 576) { int g = F - 192; wrow = w_kv  + (size_t)g * 384; bias = b_kv[g]; }
    else if (F < 720) { int g = F - 576; wrow = w_qp  + (size_t)g * 384; bias = b_qp[g]; }
    else              { int g = F - 720; wrow = w_kvp + (size_t)g * 384; bias = b_kvp[g]; }
    float a0 = bias, a1 = bias, a2 = bias, a3 = bias;
    const float4* w4 = (const float4*)wrow;
    #pragma unroll 4
    for (int c4 = 0; c4 < 96; c4++) {
      float4 wv = w4[c4];
      const float4 v0 = *(const float4*)&s16[rg * 4 + 0][c4 * 4];
      const float4 v1 = *(const float4*)&s16[rg * 4 + 1][c4 * 4];
      const float4 v2 = *(const float4*)&s16[rg * 4 + 2][c4 * 4];
      const float4 v3 = *(const float4*)&s16[rg * 4 + 3][c4 * 4];
      a0 += wv.x * v0.x + wv.y * v0.y + wv.z * v0.z + wv.w * v0.w;
      a1 += wv.x * v1.x + wv.y * v1.y + wv.z * v1.z + wv.w * v1.w;
      a2 += wv.x * v2.x + wv.y * v2.y + wv.z * v2.z + wv.w * v2.w;
      a3 += wv.x * v3.x + wv.y * v3.y + wv.z * v3.z + wv.w * v3.w;
    }
    float av[4] = {a0, a1, a2, a3};
    if (F < 576) {
      float* base;
      if (F < 192) { base = ws + WS_Q + ((F >> 4) * Nn) * 16 + (F & 15); }
      else {
        int g = F - 192, hh = g >> 5, x = g & 31;
        base = (x < 16) ? (ws + WS_K + (hh * Nn) * 16 + x)
                        : (ws + WS_V + (hh * Nn) * 16 + (x - 16));
      }
      #pragma unroll
      for (int r = 0; r < 4; r++) base[(i0 + rg * 4 + r) * 16] = av[r];
    } else {
      #pragma unroll
      for (int r = 0; r < 4; r++) praw[rg * 4 + r][f_loc] = av[r];
    }
  }
  if (fg >= 3) {
    __syncthreads();
    #pragma unroll
    for (int k = 0; k < 4; k++) {
      int tk = t + k * 256;             // 0..1023 = 16 rows x 64 triples
      int row = tk >> 6, tri = tk & 63;
      int g3 = tri * 3;
      int i = i0 + row;
      float vx = praw[row][g3], vy = praw[row][g3 + 1], vz = praw[row][g3 + 2];
      const float* R = rot16[row];
      const float* T = t16[row];
      float o0 = R[0] * vx + R[1] * vy + R[2] * vz + T[0];
      float o1 = R[3] * vx + R[4] * vy + R[5] * vz + T[1];
      float o2 = R[6] * vx + R[7] * vy + R[8] * vz + T[2];
      int pt_g = (fg - 3) * 192 + g3;   // 0..575
      float* dst;
      if (pt_g < 144) { int hh = pt_g / 12, pp = (pt_g / 3) & 3; dst = ws + WS_QP + (hh * Nn + i) * 12 + pp * 3; }
      else {
        int gg = pt_g - 144; int hh = gg / 36, pp = (gg / 3) % 12;
        dst = (pp < 4) ? (ws + WS_KP + (hh * Nn + i) * 12 + pp * 3)
                       : (ws + WS_VP + (hh * Nn + i) * 24 + (pp - 4) * 3);
      }
      dst[0] = o0; dst[1] = o1; dst[2] = o2;
    }
  }
}

// ---------------- K2: A[h][pair] = z[pair,:]·w_b[h,:] + b_b[h] (bf16 out) ----------------
__global__ __launch_bounds__(256) void k_bias(
    const float* __restrict__ z, const float* __restrict__ w_b, const float* __restrict__ b_b,
    u16* __restrict__ A)
{
  __shared__ float wb[12][128];
  __shared__ float bb[12];
  const int t = threadIdx.x;
  for (int idx = t; idx < 1536; idx += 256) wb[idx >> 7][idx & 127] = w_b[idx];
  if (t < 12) bb[t] = b_b[t];
  __syncthreads();
  const size_t pair = (size_t)blockIdx.x * 256 + t;
  const float4* zp = (const float4*)(z + pair * 128);
  float acc[12];
  #pragma unroll
  for (int h = 0; h < 12; h++) acc[h] = 0.f;
  #pragma unroll 4
  for (int c4 = 0; c4 < 32; c4++) {
    float4 zv = zp[c4];
    #pragma unroll
    for (int h = 0; h < 12; h++) {
      const float4 wv = *(const float4*)&wb[h][c4 * 4];
      acc[h] += zv.x * wv.x + zv.y * wv.y + zv.z * wv.z + zv.w * wv.w;
    }
  }
  #pragma unroll
  for (int h = 0; h < 12; h++) A[(size_t)h * NN + pair] = f2bf(acc[h] + bb[h]);
}

// ---------------- K3: logits + softmax, overwrite A with probs ----------------
__global__ __launch_bounds__(256) void k_attn(
    const float* __restrict__ ws, u16* __restrict__ A,
    const float* __restrict__ mask, const float* __restrict__ head_weights)
{
  const int h = blockIdx.x;
  const int i0 = blockIdx.y * 4;
  const int t = threadIdx.x;
  const int lane = t & 63, wv = t >> 6;
  __shared__ float qrow[4][16];
  __shared__ float qp4[4][12];
  __shared__ float mi4[4];
  __shared__ float red[4][4];
  __shared__ float Msh[4], Ssh[4];

  if (t < 64) { int r = t >> 4, c = t & 15; qrow[r][c] = ws[WS_Q + (h * Nn + i0 + r) * 16 + c]; }
  else if (t < 112) { int g = t - 64; int r = g / 12, d = g - r * 12; qp4[r][d] = ws[WS_QP + (h * Nn + i0 + r) * 12 + d]; }
  else if (t < 116) mi4[t - 112] = mask[i0 + t - 112];
  const float hw = log1pf(__expf(head_weights[h]));
  const float cpt = -0.5f * hw * 0.13608276348795434f;   // sqrt(1/54)
  __syncthreads();

  float L[4][3];
  float lmax[4] = {-1e30f, -1e30f, -1e30f, -1e30f};
  #pragma unroll
  for (int jj = 0; jj < 3; jj++) {
    const int j = t + jj * 256;
    const float4* kp = (const float4*)(ws + WS_K + (size_t)(h * Nn + j) * 16);
    float kr[16];
    #pragma unroll
    for (int u = 0; u < 4; u++) { float4 vv = kp[u]; kr[u*4] = vv.x; kr[u*4+1] = vv.y; kr[u*4+2] = vv.z; kr[u*4+3] = vv.w; }
    const float4* pp4 = (const float4*)(ws + WS_KP + (size_t)(h * Nn + j) * 12);
    float kpt[12];
    #pragma unroll
    for (int u = 0; u < 3; u++) { float4 vv = pp4[u]; kpt[u*4] = vv.x; kpt[u*4+1] = vv.y; kpt[u*4+2] = vv.z; kpt[u*4+3] = vv.w; }
    const float mj = mask[j];
    #pragma unroll
    for (int r = 0; r < 4; r++) {
      float qk = 0.f;
      #pragma unroll
      for (int c = 0; c < 16; c++) qk += qrow[r][c] * kr[c];
      float d2 = 0.f;
      #pragma unroll
      for (int d = 0; d < 12; d++) { float df = qp4[r][d] - kpt[d]; d2 += df * df; }
      float bias = bf2f(A[h * NN + (i0 + r) * Nn + j]);
      float Lv = qk * 0.14433756729740643f + 0.57735026918962584f * bias + cpt * d2
               + 100000.0f * (mi4[r] * mj - 1.0f);
      L[r][jj] = Lv;
      lmax[r] = fmaxf(lmax[r], Lv);
    }
  }
  #pragma unroll
  for (int r = 0; r < 4; r++) {
    float v = lmax[r];
    #pragma unroll
    for (int o = 32; o > 0; o >>= 1) v = fmaxf(v, __shfl_xor(v, o));
    if (lane == 0) red[wv][r] = v;
  }
  __syncthreads();
  if (t < 4) Msh[t] = fmaxf(fmaxf(red[0][t], red[1][t]), fmaxf(red[2][t], red[3][t]));
  __syncthreads();
  float lsum[4] = {0.f, 0.f, 0.f, 0.f};
  #pragma unroll
  for (int jj = 0; jj < 3; jj++) {
    #pragma unroll
    for (int r = 0; r < 4; r++) {
      float e = __expf(L[r][jj] - Msh[r]);
      L[r][jj] = e; lsum[r] += e;
    }
  }
  #pragma unroll
  for (int r = 0; r < 4; r++) {
    float v = lsum[r];
    #pragma unroll
    for (int o = 32; o > 0; o >>= 1) v += __shfl_xor(v, o);
    if (lane == 0) red[wv][r] = v;
  }
  __syncthreads();
  if (t < 4) Ssh[t] = red[0][t] + red[1][t] + red[2][t] + red[3][t];
  __syncthreads();
  float inv[4];
  #pragma unroll
  for (int r = 0; r < 4; r++) inv[r] = 1.0f / Ssh[r];
  #pragma unroll
  for (int jj = 0; jj < 3; jj++) {
    int j = t + jj * 256;
    #pragma unroll
    for (int r = 0; r < 4; r++)
      A[h * NN + (i0 + r) * Nn + j] = f2bf(L[r][jj] * inv[r]);
  }
}

// ---------------- K4a: o = a·v → cat[0:192) ----------------
__global__ __launch_bounds__(256) void k_out_o(
    const u16* __restrict__ A, float* __restrict__ ws)
{
  const int h = blockIdx.x, i0 = blockIdx.y * 16;
  const int t = threadIdx.x;
  const int ii = t >> 4, c = t & 15;
  const u16* ar = A + (size_t)h * NN + (i0 + ii) * Nn;
  const float* vb = ws + WS_V + (size_t)h * Nn * 16 + c;
  float acc = 0.f;
  #pragma unroll 4
  for (int j = 0; j < Nn; j++) acc += bf2f(ar[j]) * vb[j * 16];
  ws[WS_CAT + (size_t)(i0 + ii) * DOUT + h * 16 + c] = acc;
}

// ---------------- K4b: o_pt = a·v_pts → rotate local + norm → cat[192:576) ----------------
__global__ __launch_bounds__(192) void k_out_pt(
    const u16* __restrict__ A, const float* __restrict__ rot, const float* __restrict__ trans,
    float* __restrict__ ws)
{
  const int h = blockIdx.x, i0 = blockIdx.y * 8;
  const int t = threadIdx.x;
  __shared__ float opt[8][24];
  {
    const int ii = t / 24, d = t - (t / 24) * 24;
    const u16* ar = A + (size_t)h * NN + (i0 + ii) * Nn;
    const float* vp = ws + WS_VP + (size_t)h * Nn * 24 + d;
    float acc = 0.f;
    #pragma unroll 4
    for (int j = 0; j < Nn; j++) acc += bf2f(ar[j]) * vp[j * 24];
    opt[ii][d] = acc;
  }
  __syncthreads();
  if (t < 64) {
    const int ii = t >> 3, p = t & 7;
    const int i = i0 + ii;
    float R[9], T[3];
    #pragma unroll
    for (int u = 0; u < 9; u++) R[u] = rot[i * 9 + u];
    #pragma unroll
    for (int u = 0; u < 3; u++) T[u] = trans[i * 3 + u];
    float g0 = opt[ii][p * 3 + 0] - T[0];
    float g1 = opt[ii][p * 3 + 1] - T[1];
    float g2 = opt[ii][p * 3 + 2] - T[2];
    float lx = R[0] * g0 + R[3] * g1 + R[6] * g2;
    float ly = R[1] * g0 + R[4] * g1 + R[7] * g2;
    float lz = R[2] * g0 + R[5] * g1 + R[8] * g2;
    float* cb = ws + WS_CAT + (size_t)i * DOUT;
    cb[192 + (h * 8 + p) * 3 + 0] = lx;
    cb[192 + (h * 8 + p) * 3 + 1] = ly;
    cb[192 + (h * 8 + p) * 3 + 2] = lz;
    cb[480 + h * 8 + p] = sqrtf(lx * lx + ly * ly + lz * lz + 1e-8f);
  }
}

// ---------------- K4c: o_pair = a·z → cat[576:2112) ----------------
__global__ __launch_bounds__(256) void k_out_pair(
    const float* __restrict__ z, const u16* __restrict__ A, float* __restrict__ ws)
{
  const int i = blockIdx.x;
  const int t = threadIdx.x;
  __shared__ u16 aL[12 * 768];
  __shared__ float zch[16][128];
  __shared__ float af[12][16];
  const int c = t & 127, grp = t >> 7;   // grp 0..1 (6 heads each)

  for (int idx = t; idx < 4608; idx += 256) {   // 12*384 u32
    int hh = idx / 384, u = idx - hh * 384;
    ((u32*)aL)[hh * 384 + u] = ((const u32*)(A + (size_t)hh * NN + i * Nn))[u];
  }
  float acc[6];
  #pragma unroll
  for (int hh = 0; hh < 6; hh++) acc[hh] = 0.f;

  for (int jb = 0; jb < 48; jb++) {
    __syncthreads();
    const float4* zsrc = (const float4*)(z + ((size_t)i * Nn + jb * 16) * 128);
    #pragma unroll
    for (int k = 0; k < 2; k++) {
      int idx = t + k * 256;                 // 0..511 float4
      int row = idx >> 5, c4 = idx & 31;
      *(float4*)&zch[row][c4 * 4] = zsrc[idx];
    }
    if (t < 192) af[t >> 4][t & 15] = bf2f(aL[(t >> 4) * 768 + jb * 16 + (t & 15)]);
    __syncthreads();
    #pragma unroll 4
    for (int r = 0; r < 16; r++) {
      float zv = zch[r][c];
      #pragma unroll
      for (int hh = 0; hh < 6; hh++)
        acc[hh] += af[grp * 6 + hh][r] * zv;
    }
  }
  float* cb = ws + WS_CAT + (size_t)i * DOUT + 576;
  #pragma unroll
  for (int hh = 0; hh < 6; hh++)
    cb[(grp * 6 + hh) * 128 + c] = acc[hh];
}

// ---------------- K5: out = cat @ w_out.T + b_out ----------------
__global__ __launch_bounds__(256) void k_final(
    const float* __restrict__ ws, const float* __restrict__ w_out, const float* __restrict__ b_out,
    float* __restrict__ outp)
{
  const int i0 = blockIdx.x * 16, c0 = blockIdx.y * 32;
  const int t = threadIdx.x;
  const int ci = t & 31, ig = t >> 5;
  __shared__ float wch[32][65];
  __shared__ float cch[16][64];
  float acc0 = 0.f, acc1 = 0.f;
  for (int dc = 0; dc < 33; dc++) {
    __syncthreads();
    #pragma unroll
    for (int k = 0; k < 8; k++) {
      int idx = t + k * 256;                  // 0..2047
      int r = idx >> 6, u = idx & 63;
      wch[r][u] = w_out[(size_t)(c0 + r) * DOUT + dc * 64 + u];
    }
    #pragma unroll
    for (int k = 0; k < 4; k++) {
      int idx = t + k * 256;                  // 0..1023
      int r = idx >> 6, u = idx & 63;
      cch[r][u] = ws[WS_CAT + (size_t)(i0 + r) * DOUT + dc * 64 + u];
    }
    __syncthreads();
    #pragma unroll 8
    for (int d = 0; d < 64; d++) {
      float w = wch[ci][d];
      acc0 += cch[ig][d] * w;
      acc1 += cch[ig + 8][d] * w;
    }
  }
  float bo = b_out[c0 + ci];
  outp[(size_t)(i0 + ig) * 384 + c0 + ci]     = acc0 + bo;
  outp[(size_t)(i0 + ig + 8) * 384 + c0 + ci] = acc1 + bo;
}

extern "C" void kernel_launch(void* const* d_in, const int* in_sizes, int n_in,
                              void* d_out, int out_size, void* d_ws, size_t ws_size,
                              hipStream_t stream)
{
  const float* s      = (const float*)d_in[0];
  const float* z      = (const float*)d_in[1];
  const float* rot    = (const float*)d_in[2];
  const float* trans  = (const float*)d_in[3];
  const float* mask   = (const float*)d_in[4];
  const float* w_q    = (const float*)d_in[5];
  const float* b_q    = (const float*)d_in[6];
  const float* w_kv   = (const float*)d_in[7];
  const float* b_kv   = (const float*)d_in[8];
  const float* w_qp   = (const float*)d_in[9];
  const float* b_qp   = (const float*)d_in[10];
  const float* w_kvp  = (const float*)d_in[11];
  const float* b_kvp  = (const float*)d_in[12];
  const float* w_b    = (const float*)d_in[13];
  const float* b_b    = (const float*)d_in[14];
  const float* hwts   = (const float*)d_in[15];
  const float* w_out  = (const float*)d_in[16];
  const float* b_out  = (const float*)d_in[17];
  float* ws = (float*)d_ws;
  u16* A = (u16*)(ws + WS_A);
  float* outp = (float*)d_out;

  k_proj<<<dim3(48, 6), dim3(256), 0, stream>>>(s, rot, trans, w_q, b_q, w_kv, b_kv,
                                                w_qp, b_qp, w_kvp, b_kvp, ws);
  k_bias<<<dim3(2304), dim3(256), 0, stream>>>(z, w_b, b_b, A);
  k_attn<<<dim3(12, 192), dim3(256), 0, stream>>>(ws, A, mask, hwts);
  k_out_o<<<dim3(12, 48), dim3(256), 0, stream>>>(A, ws);
  k_out_pt<<<dim3(12, 96), dim3(192), 0, stream>>>(A, rot, trans, ws);
  k_out_pair<<<dim3(768), dim3(256), 0, stream>>>(z, A, ws);
  k_final<<<dim3(48, 12), dim3(256), 0, stream>>>(ws, w_out, b_out, outp);
}

// Round 3
// 797.900 us; speedup vs baseline: 1.1776x; 1.1776x over previous
//
#include <hip/hip_runtime.h>
#include <math.h>

#define Nn 768
#define NN 589824          // 768*768
#define DOUT 2112

// ws float offsets
#define WS_Q   0           // fp32 [12][768][16]
#define WS_K   147456      // fp32 [12][768][16]
#define WS_QP  442368      // fp32 [12][768][12]
#define WS_KP  552960      // fp32 [12][768][12]
#define WS_CAT 884736      // fp32 [768][2112]
#define WS_A   2506752     // bf16 [12][768][768] stored as u16 (3538944 floats)
#define WS_VT  6045696     // bf16 [12][40][768] transposed V|VP rows

typedef unsigned short u16;
typedef unsigned int u32;

using bf16x8 = __attribute__((ext_vector_type(8))) short;
using f32x4  = __attribute__((ext_vector_type(4))) float;

__device__ __forceinline__ float bf2f(u16 u) {
  union { float f; u32 i; } x; x.i = ((u32)u) << 16; return x.f;
}
__device__ __forceinline__ u16 f2bf(float f) {
  union { float f; u32 i; } x; x.f = f;
  u32 r = x.i + 0x7FFFu + ((x.i >> 16) & 1u);
  return (u16)(r >> 16);
}

// ---------------- K1: projections q,k,v + rotated points ----------------
// grid (48 i-tiles, 6 feature-groups of 192), block 256
__global__ __launch_bounds__(256) void k_proj(
    const float* __restrict__ s, const float* __restrict__ rot, const float* __restrict__ trans,
    const float* __restrict__ w_q, const float* __restrict__ b_q,
    const float* __restrict__ w_kv, const float* __restrict__ b_kv,
    const float* __restrict__ w_qp, const float* __restrict__ b_qp,
    const float* __restrict__ w_kvp, const float* __restrict__ b_kvp,
    float* __restrict__ ws)
{
  __shared__ float s16[16][384];
  __shared__ float praw[16][192];
  __shared__ float rot16[16][9];
  __shared__ float t16[16][3];
  const int t = threadIdx.x;
  const int ib = blockIdx.x, fg = blockIdx.y;
  const int i0 = ib * 16;
  u16* VT = (u16*)(ws + WS_VT);

  {
    const float4* sp = (const float4*)(s + (size_t)i0 * 384);
    float4* dp = (float4*)&s16[0][0];
    for (int idx = t; idx < 1536; idx += 256) dp[idx] = sp[idx];
  }
  if (fg >= 3) {
    if (t < 144) rot16[t / 9][t % 9] = rot[i0 * 9 + t];
    else if (t < 192) { int g = t - 144; t16[g / 3][g % 3] = trans[i0 * 3 + g]; }
  }
  __syncthreads();

  const int rg = t >> 6;          // row group 0..3 (rows rg*4 .. rg*4+3)
  const int fl = t & 63;
  for (int p = 0; p < 3; p++) {
    const int f_loc = p * 64 + fl;        // 0..191
    const int F = fg * 192 + f_loc;       // global feature 0..1151
    const float* wrow; float bias;
    if (F < 192)      { wrow = w_q   + (size_t)F * 384;          bias = b_q[F]; }
    else if (F < 576) { int g = F - 192; wrow = w_kv  + (size_t)g * 384; bias = b_kv[g]; }
    else if (F < 720) { int g = F - 576; wrow = w_qp  + (size_t)g * 384; bias = b_qp[g]; }
    else              { int g = F - 720; wrow = w_kvp + (size_t)g * 384; bias = b_kvp[g]; }
    float a0 = bias, a1 = bias, a2 = bias, a3 = bias;
    const float4* w4 = (const float4*)wrow;
    #pragma unroll 4
    for (int c4 = 0; c4 < 96; c4++) {
      float4 wv = w4[c4];
      const float4 v0 = *(const float4*)&s16[rg * 4 + 0][c4 * 4];
      const float4 v1 = *(const float4*)&s16[rg * 4 + 1][c4 * 4];
      const float4 v2 = *(const float4*)&s16[rg * 4 + 2][c4 * 4];
      const float4 v3 = *(const float4*)&s16[rg * 4 + 3][c4 * 4];
      a0 += wv.x * v0.x + wv.y * v0.y + wv.z * v0.z + wv.w * v0.w;
      a1 += wv.x * v1.x + wv.y * v1.y + wv.z * v1.z + wv.w * v1.w;
      a2 += wv.x * v2.x + wv.y * v2.y + wv.z * v2.z + wv.w * v2.w;
      a3 += wv.x * v3.x + wv.y * v3.y + wv.z * v3.z + wv.w * v3.w;
    }
    float av[4] = {a0, a1, a2, a3};
    if (F < 576) {
      if (F < 192) {
        float* base = ws + WS_Q + ((F >> 4) * Nn) * 16 + (F & 15);
        #pragma unroll
        for (int r = 0; r < 4; r++) base[(i0 + rg * 4 + r) * 16] = av[r];
      } else {
        int g = F - 192, hh = g >> 5, x = g & 31;
        if (x < 16) {
          float* base = ws + WS_K + (hh * Nn) * 16 + x;
          #pragma unroll
          for (int r = 0; r < 4; r++) base[(i0 + rg * 4 + r) * 16] = av[r];
        } else {
          u16* vt = VT + (size_t)(hh * 40 + (x - 16)) * 768;
          #pragma unroll
          for (int r = 0; r < 4; r++) vt[i0 + rg * 4 + r] = f2bf(av[r]);
        }
      }
    } else {
      #pragma unroll
      for (int r = 0; r < 4; r++) praw[rg * 4 + r][f_loc] = av[r];
    }
  }
  if (fg >= 3) {
    __syncthreads();
    #pragma unroll
    for (int k = 0; k < 4; k++) {
      int tk = t + k * 256;             // 0..1023 = 16 rows x 64 triples
      int row = tk >> 6, tri = tk & 63;
      int g3 = tri * 3;
      int i = i0 + row;
      float vx = praw[row][g3], vy = praw[row][g3 + 1], vz = praw[row][g3 + 2];
      const float* R = rot16[row];
      const float* T = t16[row];
      float o0 = R[0] * vx + R[1] * vy + R[2] * vz + T[0];
      float o1 = R[3] * vx + R[4] * vy + R[5] * vz + T[1];
      float o2 = R[6] * vx + R[7] * vy + R[8] * vz + T[2];
      int pt_g = (fg - 3) * 192 + g3;   // 0..575
      if (pt_g < 144) {
        int hh = pt_g / 12, pp = (pt_g / 3) & 3;
        float* dst = ws + WS_QP + (hh * Nn + i) * 12 + pp * 3;
        dst[0] = o0; dst[1] = o1; dst[2] = o2;
      } else {
        int gg = pt_g - 144; int hh = gg / 36, pp = (gg / 3) % 12;
        if (pp < 4) {
          float* dst = ws + WS_KP + (hh * Nn + i) * 12 + pp * 3;
          dst[0] = o0; dst[1] = o1; dst[2] = o2;
        } else {
          u16* vt = VT + (size_t)(hh * 40 + 16 + (pp - 4) * 3) * 768 + i;
          vt[0] = f2bf(o0); vt[768] = f2bf(o1); vt[1536] = f2bf(o2);
        }
      }
    }
  }
}

// ---------------- K2: A[h][pair] = z[pair,:]·w_b[h,:] + b_b[h] (bf16 out) ----------------
__global__ __launch_bounds__(256) void k_bias(
    const float* __restrict__ z, const float* __restrict__ w_b, const float* __restrict__ b_b,
    u16* __restrict__ A)
{
  __shared__ float wb[12][128];
  __shared__ float bb[12];
  const int t = threadIdx.x;
  for (int idx = t; idx < 1536; idx += 256) wb[idx >> 7][idx & 127] = w_b[idx];
  if (t < 12) bb[t] = b_b[t];
  __syncthreads();
  const size_t pair = (size_t)blockIdx.x * 256 + t;
  const float4* zp = (const float4*)(z + pair * 128);
  float acc[12];
  #pragma unroll
  for (int h = 0; h < 12; h++) acc[h] = 0.f;
  #pragma unroll 4
  for (int c4 = 0; c4 < 32; c4++) {
    float4 zv = zp[c4];
    #pragma unroll
    for (int h = 0; h < 12; h++) {
      const float4 wv = *(const float4*)&wb[h][c4 * 4];
      acc[h] += zv.x * wv.x + zv.y * wv.y + zv.z * wv.z + zv.w * wv.w;
    }
  }
  #pragma unroll
  for (int h = 0; h < 12; h++) A[(size_t)h * NN + pair] = f2bf(acc[h] + bb[h]);
}

// ---------------- K3: logits + softmax, overwrite A with probs ----------------
__global__ __launch_bounds__(256) void k_attn(
    const float* __restrict__ ws, u16* __restrict__ A,
    const float* __restrict__ mask, const float* __restrict__ head_weights)
{
  const int h = blockIdx.x;
  const int i0 = blockIdx.y * 4;
  const int t = threadIdx.x;
  const int lane = t & 63, wv = t >> 6;
  __shared__ float qrow[4][16];
  __shared__ float qp4[4][12];
  __shared__ float mi4[4];
  __shared__ float red[4][4];
  __shared__ float Msh[4], Ssh[4];

  if (t < 64) { int r = t >> 4, c = t & 15; qrow[r][c] = ws[WS_Q + (h * Nn + i0 + r) * 16 + c]; }
  else if (t < 112) { int g = t - 64; int r = g / 12, d = g - r * 12; qp4[r][d] = ws[WS_QP + (h * Nn + i0 + r) * 12 + d]; }
  else if (t < 116) mi4[t - 112] = mask[i0 + t - 112];
  const float hw = log1pf(__expf(head_weights[h]));
  const float cpt = -0.5f * hw * 0.13608276348795434f;   // sqrt(1/54)
  __syncthreads();

  float L[4][3];
  float lmax[4] = {-1e30f, -1e30f, -1e30f, -1e30f};
  #pragma unroll
  for (int jj = 0; jj < 3; jj++) {
    const int j = t + jj * 256;
    const float4* kp = (const float4*)(ws + WS_K + (size_t)(h * Nn + j) * 16);
    float kr[16];
    #pragma unroll
    for (int u = 0; u < 4; u++) { float4 vv = kp[u]; kr[u*4] = vv.x; kr[u*4+1] = vv.y; kr[u*4+2] = vv.z; kr[u*4+3] = vv.w; }
    const float4* pp4 = (const float4*)(ws + WS_KP + (size_t)(h * Nn + j) * 12);
    float kpt[12];
    #pragma unroll
    for (int u = 0; u < 3; u++) { float4 vv = pp4[u]; kpt[u*4] = vv.x; kpt[u*4+1] = vv.y; kpt[u*4+2] = vv.z; kpt[u*4+3] = vv.w; }
    const float mj = mask[j];
    #pragma unroll
    for (int r = 0; r < 4; r++) {
      float qk = 0.f;
      #pragma unroll
      for (int c = 0; c < 16; c++) qk += qrow[r][c] * kr[c];
      float d2 = 0.f;
      #pragma unroll
      for (int d = 0; d < 12; d++) { float df = qp4[r][d] - kpt[d]; d2 += df * df; }
      float bias = bf2f(A[h * NN + (i0 + r) * Nn + j]);
      float Lv = qk * 0.14433756729740643f + 0.57735026918962584f * bias + cpt * d2
               + 100000.0f * (mi4[r] * mj - 1.0f);
      L[r][jj] = Lv;
      lmax[r] = fmaxf(lmax[r], Lv);
    }
  }
  #pragma unroll
  for (int r = 0; r < 4; r++) {
    float v = lmax[r];
    #pragma unroll
    for (int o = 32; o > 0; o >>= 1) v = fmaxf(v, __shfl_xor(v, o));
    if (lane == 0) red[wv][r] = v;
  }
  __syncthreads();
  if (t < 4) Msh[t] = fmaxf(fmaxf(red[0][t], red[1][t]), fmaxf(red[2][t], red[3][t]));
  __syncthreads();
  float lsum[4] = {0.f, 0.f, 0.f, 0.f};
  #pragma unroll
  for (int jj = 0; jj < 3; jj++) {
    #pragma unroll
    for (int r = 0; r < 4; r++) {
      float e = __expf(L[r][jj] - Msh[r]);
      L[r][jj] = e; lsum[r] += e;
    }
  }
  #pragma unroll
  for (int r = 0; r < 4; r++) {
    float v = lsum[r];
    #pragma unroll
    for (int o = 32; o > 0; o >>= 1) v += __shfl_xor(v, o);
    if (lane == 0) red[wv][r] = v;
  }
  __syncthreads();
  if (t < 4) Ssh[t] = red[0][t] + red[1][t] + red[2][t] + red[3][t];
  __syncthreads();
  float inv[4];
  #pragma unroll
  for (int r = 0; r < 4; r++) inv[r] = 1.0f / Ssh[r];
  #pragma unroll
  for (int jj = 0; jj < 3; jj++) {
    int j = t + jj * 256;
    #pragma unroll
    for (int r = 0; r < 4; r++)
      A[h * NN + (i0 + r) * Nn + j] = f2bf(L[r][jj] * inv[r]);
  }
}

// ---------------- K4: O_h = A_h · [V|VP]_h via MFMA; rotate+norm epilogue ----------------
// grid (48 i-tiles, 12 heads), block 192 (3 waves = 3 N-tiles of 16)
__global__ __launch_bounds__(192) void k_out_ov(
    const u16* __restrict__ A, const u16* __restrict__ VT,
    const float* __restrict__ rot, const float* __restrict__ trans,
    float* __restrict__ ws)
{
  const int ib = blockIdx.x, h = blockIdx.y;
  const int i0 = ib * 16;
  const int t = threadIdx.x;
  const int w = t >> 6, lane = t & 63;
  const int n = lane & 15, quad = lane >> 4;
  __shared__ float opt[16][26];

  const int col40 = w * 16 + n;            // 0..47, valid < 40
  const bool bvalid = col40 < 40;
  const u16* abase = A + (size_t)h * NN + (size_t)(i0 + n) * Nn + quad * 8;  // m = lane&15
  const u16* bbase = VT + (size_t)(h * 40 + (bvalid ? col40 : 0)) * 768 + quad * 8;

  f32x4 acc = {0.f, 0.f, 0.f, 0.f};
  #pragma unroll 4
  for (int kk = 0; kk < 24; kk++) {
    bf16x8 af = *(const bf16x8*)(abase + kk * 32);
    bf16x8 bf = *(const bf16x8*)(bbase + kk * 32);
    if (!bvalid) bf = bf16x8{0, 0, 0, 0, 0, 0, 0, 0};
    acc = __builtin_amdgcn_mfma_f32_16x16x32_bf16(af, bf, acc, 0, 0, 0);
  }

  const int mrow = quad * 4;               // C layout: col = lane&15, row = quad*4 + reg
  if (w == 0) {
    float* cb = ws + WS_CAT + (size_t)i0 * DOUT + h * 16 + n;
    #pragma unroll
    for (int r = 0; r < 4; r++) cb[(size_t)(mrow + r) * DOUT] = acc[r];
  } else if (w == 1 || n < 8) {
    const int col = (w - 1) * 16 + n;      // 0..23
    #pragma unroll
    for (int r = 0; r < 4; r++) opt[mrow + r][col] = acc[r];
  }
  __syncthreads();
  if (t < 128) {
    const int ii = t >> 3, p = t & 7;
    const int i = i0 + ii;
    float R[9], T[3];
    #pragma unroll
    for (int u = 0; u < 9; u++) R[u] = rot[i * 9 + u];
    #pragma unroll
    for (int u = 0; u < 3; u++) T[u] = trans[i * 3 + u];
    float g0 = opt[ii][p * 3 + 0] - T[0];
    float g1 = opt[ii][p * 3 + 1] - T[1];
    float g2 = opt[ii][p * 3 + 2] - T[2];
    float lx = R[0] * g0 + R[3] * g1 + R[6] * g2;
    float ly = R[1] * g0 + R[4] * g1 + R[7] * g2;
    float lz = R[2] * g0 + R[5] * g1 + R[8] * g2;
    float* cb = ws + WS_CAT + (size_t)i * DOUT;
    cb[192 + (h * 8 + p) * 3 + 0] = lx;
    cb[192 + (h * 8 + p) * 3 + 1] = ly;
    cb[192 + (h * 8 + p) * 3 + 2] = lz;
    cb[480 + h * 8 + p] = sqrtf(lx * lx + ly * ly + lz * lz + 1e-8f);
  }
}

// ---------------- K5: o_pair = a·z → cat[576:2112), register-prefetch dbuf ----------------
__global__ __launch_bounds__(256) void k_out_pair(
    const float* __restrict__ z, const u16* __restrict__ A, float* __restrict__ ws)
{
  const int i = blockIdx.x;
  const int t = threadIdx.x;
  __shared__ u16 aL[12 * 768];
  __shared__ float zch[16][128];
  __shared__ float af[12][16];
  const int c = t & 127, grp = t >> 7;   // grp 0..1 (6 heads each)

  for (int idx = t; idx < 4608; idx += 256) {   // 12*384 u32
    int hh = idx / 384, u = idx - hh * 384;
    ((u32*)aL)[hh * 384 + u] = ((const u32*)(A + (size_t)hh * NN + i * Nn))[u];
  }
  float acc[6];
  #pragma unroll
  for (int hh = 0; hh < 6; hh++) acc[hh] = 0.f;

  const float4* zsrc = (const float4*)(z + (size_t)i * Nn * 128);
  float4 p0 = zsrc[t], p1 = zsrc[t + 256];    // prefetch chunk 0

  for (int jb = 0; jb < 48; jb++) {
    __syncthreads();
    {
      int i0x = t, i1x = t + 256;
      *(float4*)&zch[i0x >> 5][(i0x & 31) * 4] = p0;
      *(float4*)&zch[i1x >> 5][(i1x & 31) * 4] = p1;
    }
    if (t < 192) af[t >> 4][t & 15] = bf2f(aL[(t >> 4) * 768 + jb * 16 + (t & 15)]);
    __syncthreads();
    if (jb + 1 < 48) {
      const float4* zn = zsrc + (size_t)(jb + 1) * 512;
      p0 = zn[t]; p1 = zn[t + 256];
    }
    #pragma unroll 4
    for (int r = 0; r < 16; r++) {
      float zv = zch[r][c];
      #pragma unroll
      for (int hh = 0; hh < 6; hh++)
        acc[hh] += af[grp * 6 + hh][r] * zv;
    }
  }
  float* cb = ws + WS_CAT + (size_t)i * DOUT + 576;
  #pragma unroll
  for (int hh = 0; hh < 6; hh++)
    cb[(grp * 6 + hh) * 128 + c] = acc[hh];
}

// ---------------- K6: out = cat @ w_out.T + b_out ----------------
__global__ __launch_bounds__(256) void k_final(
    const float* __restrict__ ws, const float* __restrict__ w_out, const float* __restrict__ b_out,
    float* __restrict__ outp)
{
  const int i0 = blockIdx.x * 16, c0 = blockIdx.y * 32;
  const int t = threadIdx.x;
  const int ci = t & 31, ig = t >> 5;
  __shared__ float wch[32][65];
  __shared__ float cch[16][64];
  float acc0 = 0.f, acc1 = 0.f;
  for (int dc = 0; dc < 33; dc++) {
    __syncthreads();
    #pragma unroll
    for (int k = 0; k < 8; k++) {
      int idx = t + k * 256;                  // 0..2047
      int r = idx >> 6, u = idx & 63;
      wch[r][u] = w_out[(size_t)(c0 + r) * DOUT + dc * 64 + u];
    }
    #pragma unroll
    for (int k = 0; k < 4; k++) {
      int idx = t + k * 256;                  // 0..1023
      int r = idx >> 6, u = idx & 63;
      cch[r][u] = ws[WS_CAT + (size_t)(i0 + r) * DOUT + dc * 64 + u];
    }
    __syncthreads();
    #pragma unroll 8
    for (int d = 0; d < 64; d++) {
      float w = wch[ci][d];
      acc0 += cch[ig][d] * w;
      acc1 += cch[ig + 8][d] * w;
    }
  }
  float bo = b_out[c0 + ci];
  outp[(size_t)(i0 + ig) * 384 + c0 + ci]     = acc0 + bo;
  outp[(size_t)(i0 + ig + 8) * 384 + c0 + ci] = acc1 + bo;
}

extern "C" void kernel_launch(void* const* d_in, const int* in_sizes, int n_in,
                              void* d_out, int out_size, void* d_ws, size_t ws_size,
                              hipStream_t stream)
{
  const float* s      = (const float*)d_in[0];
  const float* z      = (const float*)d_in[1];
  const float* rot    = (const float*)d_in[2];
  const float* trans  = (const float*)d_in[3];
  const float* mask   = (const float*)d_in[4];
  const float* w_q    = (const float*)d_in[5];
  const float* b_q    = (const float*)d_in[6];
  const float* w_kv   = (const float*)d_in[7];
  const float* b_kv   = (const float*)d_in[8];
  const float* w_qp   = (const float*)d_in[9];
  const float* b_qp   = (const float*)d_in[10];
  const float* w_kvp  = (const float*)d_in[11];
  const float* b_kvp  = (const float*)d_in[12];
  const float* w_b    = (const float*)d_in[13];
  const float* b_b    = (const float*)d_in[14];
  const float* hwts   = (const float*)d_in[15];
  const float* w_out  = (const float*)d_in[16];
  const float* b_out  = (const float*)d_in[17];
  float* ws = (float*)d_ws;
  u16* A = (u16*)(ws + WS_A);
  u16* VT = (u16*)(ws + WS_VT);
  float* outp = (float*)d_out;

  k_proj<<<dim3(48, 6), dim3(256), 0, stream>>>(s, rot, trans, w_q, b_q, w_kv, b_kv,
                                                w_qp, b_qp, w_kvp, b_kvp, ws);
  k_bias<<<dim3(2304), dim3(256), 0, stream>>>(z, w_b, b_b, A);
  k_attn<<<dim3(12, 192), dim3(256), 0, stream>>>(ws, A, mask, hwts);
  k_out_ov<<<dim3(48, 12), dim3(192), 0, stream>>>(A, VT, rot, trans, ws);
  k_out_pair<<<dim3(768), dim3(256), 0, stream>>>(z, A, ws);
  k_final<<<dim3(48, 12), dim3(256), 0, stream>>>(ws, w_out, b_out, outp);
}